// Round 6
// baseline (903.370 us; speedup 1.0000x reference)
//
#include <hip/hip_runtime.h>
#include <hip/hip_bf16.h>

// Problem constants (fixed by the reference)
#define B_ 1024
#define L_ 32
#define M_ 128
#define N_ 4096
#define S_ 32
#define ROWS (B_ * L_)          // 32768 rows of length N_

typedef __attribute__((ext_vector_type(8))) short    short8_t;   // 8 bf16 (4 VGPR)
typedef __attribute__((ext_vector_type(8))) unsigned short ushort8_t;
typedef __attribute__((ext_vector_type(4))) float    f32x4;

__device__ __forceinline__ unsigned short f2bf(float x) {  // RNE bf16
    unsigned u = __float_as_uint(x);
    unsigned r = (u + 0x7FFFu + ((u >> 16) & 1u)) >> 16;
    return (unsigned short)r;
}
__device__ __forceinline__ float bf2f(unsigned short h) {
    return __uint_as_float((unsigned)h << 16);
}

// ---------------------------------------------------------------------------
// K0: transpose W_d [L][M][N] -> W_dT [L][N][M] (runs AFTER encoder; WdT
// aliases the Wbf region)
// ---------------------------------------------------------------------------
__global__ __launch_bounds__(256) void transpose_wd(const float* __restrict__ Wd,
                                                    float* __restrict__ WdT) {
    __shared__ float t[32][33];
    int l = blockIdx.z;
    int n0 = blockIdx.x * 32, m0 = blockIdx.y * 32;
    int tx = threadIdx.x & 31, ty = threadIdx.x >> 5;
    const float* src = Wd + (size_t)l * M_ * N_;
    for (int i = ty; i < 32; i += 8)
        t[i][tx] = src[(size_t)(m0 + i) * N_ + n0 + tx];
    __syncthreads();
    float* dst = WdT + (size_t)l * N_ * M_;
    for (int i = ty; i < 32; i += 8)
        dst[(size_t)(n0 + i) * M_ + m0 + tx] = t[tx][i];
}

// ---------------------------------------------------------------------------
// K0b: c[l][n] = dot(b_d[l], W_e[l][n])
// ---------------------------------------------------------------------------
__global__ __launch_bounds__(256) void bias_dot(const float* __restrict__ We,
                                                const float* __restrict__ bd,
                                                float* __restrict__ c) {
    int l = blockIdx.y;
    int tid = threadIdx.x;
    int nl = tid >> 4, l16 = tid & 15;
    int n = blockIdx.x * 16 + nl;
    const float* w = We + ((size_t)l * N_ + n) * M_ + l16 * 8;
    const float* b = bd + l * M_ + l16 * 8;
    float4 w0 = *(const float4*)(w), w1 = *(const float4*)(w + 4);
    float4 b0 = *(const float4*)(b), b1 = *(const float4*)(b + 4);
    float s = w0.x*b0.x + w0.y*b0.y + w0.z*b0.z + w0.w*b0.w
            + w1.x*b1.x + w1.y*b1.y + w1.z*b1.z + w1.w*b1.w;
    #pragma unroll
    for (int o = 8; o > 0; o >>= 1) s += __shfl_xor(s, o, 64);
    if (l16 == 0) c[(size_t)l * N_ + n] = s;
}

// ---------------------------------------------------------------------------
// P1: split kin -> Abf [l][b][256] bf16: seg0 = a1 = bf16(k), seg1 = a2 = bf16(k-a1)
// ---------------------------------------------------------------------------
__global__ __launch_bounds__(256) void prep_a(const float* __restrict__ kin,
                                              unsigned short* __restrict__ Abf) {
    int g = blockIdx.x * 256 + threadIdx.x;       // over B*L*M
    int b = g >> 12, l = (g >> 7) & 31, m = g & 127;
    float x = kin[g];
    unsigned short a1 = f2bf(x);
    unsigned short a2 = f2bf(x - bf2f(a1));
    size_t base = ((size_t)l * B_ + b) * 256;
    Abf[base + m]       = a1;
    Abf[base + 128 + m] = a2;
}

// P2: split We -> Wbf [l][n][256] bf16: seg0 = w1, seg1 = w2
__global__ __launch_bounds__(256) void prep_w(const float* __restrict__ We,
                                              unsigned short* __restrict__ Wbf) {
    int g = blockIdx.x * 256 + threadIdx.x;       // over L*N*M
    int l = g >> 19, n = (g >> 7) & 4095, m = g & 127;
    float x = We[g];
    unsigned short w1 = f2bf(x);
    unsigned short w2 = f2bf(x - bf2f(w1));
    size_t base = ((size_t)l * N_ + n) * 256;
    Wbf[base + m]       = w1;
    Wbf[base + 128 + m] = w2;
}

// ---------------------------------------------------------------------------
// K1: encoder approx GEMM via MFMA bf16, 3-term split (unchanged from round 4)
// ---------------------------------------------------------------------------
__device__ __forceinline__ int swz(int row) { return (row & 3) ^ ((row >> 2) & 3); }

__global__ __launch_bounds__(256) void encoder_mfma(const unsigned short* __restrict__ Abf,
                                                    const unsigned short* __restrict__ Wbf,
                                                    const float* __restrict__ cvec,
                                                    unsigned short* __restrict__ y16) {
    const int l   = blockIdx.z;
    const int bn0 = blockIdx.x * 128;
    const int bm0 = blockIdx.y * 128;
    __shared__ __align__(16) unsigned short As[128 * 32];
    __shared__ __align__(16) unsigned short Bs[128 * 32];
    const int tid  = threadIdx.x;
    const int lane = tid & 63, wave = tid >> 6;
    const int wr = wave >> 1, wc = wave & 1;

    const unsigned short* Ab = Abf + ((size_t)l * B_ + bm0) * 256;
    const unsigned short* Wb = Wbf + ((size_t)l * N_ + bn0) * 256;

    auto stage = [&](int kA0, int kW0) {
        #pragma unroll
        for (int i = 0; i < 2; ++i) {
            int p   = i * 256 + tid;
            int row = p >> 2;
            int lc  = (p & 3) ^ swz(row);
            const unsigned short* g = Ab + (size_t)row * 256 + kA0 + lc * 8;
            unsigned dst = (unsigned)((i * 256 + (tid & ~63)) * 16);
            __builtin_amdgcn_global_load_lds(
                (const __attribute__((address_space(1))) void*)g,
                (__attribute__((address_space(3))) void*)((char*)As + dst), 16, 0, 0);
        }
        #pragma unroll
        for (int i = 0; i < 2; ++i) {
            int p   = i * 256 + tid;
            int row = p >> 2;
            int lc  = (p & 3) ^ swz(row);
            const unsigned short* g = Wb + (size_t)row * 256 + kW0 + lc * 8;
            unsigned dst = (unsigned)((i * 256 + (tid & ~63)) * 16);
            __builtin_amdgcn_global_load_lds(
                (const __attribute__((address_space(1))) void*)g,
                (__attribute__((address_space(3))) void*)((char*)Bs + dst), 16, 0, 0);
        }
    };

    f32x4 acc[4][4];
    #pragma unroll
    for (int i = 0; i < 4; ++i)
        #pragma unroll
        for (int j = 0; j < 4; ++j) acc[i][j] = (f32x4){0.f, 0.f, 0.f, 0.f};

    stage(0, 0);
    __syncthreads();

    #pragma unroll
    for (int t = 0; t < 12; ++t) {
        short8_t aF[4], bF[4];
        const int kg = lane >> 4;
        #pragma unroll
        for (int mt = 0; mt < 4; ++mt) {
            int row = wr * 64 + mt * 16 + (lane & 15);
            int pc  = kg ^ swz(row);
            aF[mt] = *reinterpret_cast<const short8_t*>(As + row * 32 + pc * 8);
        }
        #pragma unroll
        for (int nt = 0; nt < 4; ++nt) {
            int row = wc * 64 + nt * 16 + (lane & 15);
            int pc  = kg ^ swz(row);
            bF[nt] = *reinterpret_cast<const short8_t*>(Bs + row * 32 + pc * 8);
        }
        #pragma unroll
        for (int mt = 0; mt < 4; ++mt)
            #pragma unroll
            for (int nt = 0; nt < 4; ++nt)
                acc[mt][nt] = __builtin_amdgcn_mfma_f32_16x16x32_bf16(
                    aF[mt], bF[nt], acc[mt][nt], 0, 0, 0);

        if (t < 11) {
            int tn  = t + 1;
            int seg = tn >> 2, r = (tn & 3) * 32;
            int ka  = (seg == 2) ? 128 + r : r;
            int kw  = (seg == 1) ? 128 + r : r;
            __syncthreads();
            stage(ka, kw);
            __syncthreads();
        }
    }

    #pragma unroll
    for (int nt = 0; nt < 4; ++nt) {
        int n = bn0 + wc * 64 + nt * 16 + (lane & 15);
        float cj = cvec[(size_t)l * N_ + n];
        #pragma unroll
        for (int mt = 0; mt < 4; ++mt) {
            #pragma unroll
            for (int j = 0; j < 4; ++j) {
                int b = bm0 + wr * 64 + mt * 16 + (lane >> 4) * 4 + j;
                y16[((size_t)(b * L_ + l)) * 8192 + n] = f2bf(acc[mt][nt][j] - cj);
            }
        }
    }
}

// ---------------------------------------------------------------------------
// K2: exact top-32.
//  - approx bf16 loads -> convert -> sched_barrier -> zero-store full row
//    (loads provably complete into regs before the overwriting stores issue)
//  - bisect with ONE barrier/iter, tighten until count <= 40
//  - pool candidates >= lo - MARGIN (8e-4 >= 2*eps, proven + validated r4)
//  - stage pool We rows into transposed LDS [m][e] (pitch 65, conflict-free)
//  - exact recompute: thread-per-candidate ASCENDING-m scalar fmaf chain from
//    LDS -- bit-identical to the chain that passed rounds 1-4
//  - exact all-pairs rank, lowest-index tie-break; winners scatter exact values
// ---------------------------------------------------------------------------
#define POOL 64
#define MARGIN 8e-4f

__global__ __launch_bounds__(256) void topk_kernel(float* __restrict__ y,
                                                   const float* __restrict__ We,
                                                   const float* __restrict__ kin,
                                                   const float* __restrict__ cvec,
                                                   int* __restrict__ cidx,
                                                   float* __restrict__ cval) {
    const int row = blockIdx.x;                 // row = b*L + l
    const int b = row >> 5, l = row & 31;
    const unsigned short* ya = (const unsigned short*)y + (size_t)row * 8192;
    float* yo = y + (size_t)row * N_;
    const int tid  = threadIdx.x;
    const int wave = tid >> 6, lane = tid & 63;

    __shared__ float LdsW[M_ * 65];             // [m][e] transposed, pitch 65 (33.3KB)
    __shared__ float kinL[M_];
    __shared__ float red_f[4];
    __shared__ int   red_i[2][4];
    __shared__ int   pidxS[POOL];
    __shared__ float pexS[POOL];
    __shared__ int   pcnt;

    if (tid < M_) kinL[tid] = kin[((size_t)b * L_ + l) * M_ + tid];
    if (tid == 0) pcnt = 0;

    // load 16 approx values (two 16B loads), thread-local slots
    ushort8_t u0 = *reinterpret_cast<const ushort8_t*>(ya + tid * 8);
    ushort8_t u1 = *reinterpret_cast<const ushort8_t*>(ya + 2048 + tid * 8);
    float a[16];
    #pragma unroll
    for (int i = 0; i < 8; ++i) {
        a[i]     = fabsf(bf2f(u0[i]));
        a[8 + i] = fabsf(bf2f(u1[i]));
    }
    // Hard scheduling fence: the conversions above force the loads' waitcnt;
    // nothing below may be hoisted above this point. Then overwrite the row
    // with zeros (each thread covers exactly the bytes it loaded, + upper 8KB).
    __builtin_amdgcn_sched_barrier(0);
    {
        float4 z = {0.f, 0.f, 0.f, 0.f};
        #pragma unroll
        for (int i = 0; i < 4; ++i)
            *reinterpret_cast<float4*>(yo + 4 * (tid + i * 256)) = z;
    }

    // block max (one barrier)
    float mx = 0.0f;
    #pragma unroll
    for (int i = 0; i < 16; ++i) mx = fmaxf(mx, a[i]);
    #pragma unroll
    for (int o = 32; o > 0; o >>= 1) mx = fmaxf(mx, __shfl_xor(mx, o, 64));
    if (lane == 0) red_f[wave] = mx;
    __syncthreads();
    mx = fmaxf(fmaxf(red_f[0], red_f[1]), fmaxf(red_f[2], red_f[3]));

    // bisect: invariant count(a >= lo) >= 32; tighten until count <= 40.
    // ONE barrier per iteration (alternating slots).
    float lo = 0.0f, hi = mx;
    int cl = N_;
    for (int it = 0; it < 30 && cl > 40; ++it) {
        float t = 0.5f * (lo + hi);
        int c = 0;
        #pragma unroll
        for (int i = 0; i < 16; ++i) c += (a[i] >= t) ? 1 : 0;
        #pragma unroll
        for (int o = 32; o > 0; o >>= 1) c += __shfl_xor(c, o, 64);
        if (lane == 0) red_i[it & 1][wave] = c;
        __syncthreads();
        c = red_i[it & 1][0] + red_i[it & 1][1] + red_i[it & 1][2] + red_i[it & 1][3];
        if (c >= S_) { lo = t; cl = c; } else { hi = t; }
    }

    // pool: everything with approx >= lo - MARGIN (provably covers exact top-32)
    const float th = lo - MARGIN;
    #pragma unroll
    for (int i = 0; i < 16; ++i) {
        if (a[i] >= th) {
            int p = atomicAdd(&pcnt, 1);
            if (p < POOL) pidxS[p] = (i < 8) ? (tid * 8 + i) : (2048 + tid * 8 + i - 8);
        }
    }
    __syncthreads();
    int c = pcnt < POOL ? pcnt : POOL;

    // stage pool We rows into LDS, transposed: LdsW[m*65+e] = We[l][n_e][m].
    // global: 128 consecutive threads read one contiguous 512B row (coalesced);
    // LDS banks (m*65+e)%32 = (m+e)%32 -> conflict-free.
    for (int idx = tid; idx < c * M_; idx += 256) {
        int e = idx >> 7, m = idx & 127;
        LdsW[m * 65 + e] = We[((size_t)l * N_ + pidxS[e]) * M_ + m];
    }
    __syncthreads();

    // exact recompute: ascending-m scalar fmaf chain (bit-identical to r1-r4),
    // thread e handles candidate e, data from LDS.
    if (tid < c) {
        int n = pidxS[tid];
        float acc = -cvec[(size_t)l * N_ + n];
        #pragma unroll 8
        for (int m = 0; m < M_; ++m)
            acc = fmaf(LdsW[m * 65 + tid], kinL[m], acc);
        pexS[tid] = acc;
    }
    __syncthreads();

    // exact rank (lowest-index tie-break), emit winners
    for (int e = tid; e < c; e += 256) {
        float ae = fabsf(pexS[e]);
        int   ne = pidxS[e];
        int rank = 0;
        for (int j = 0; j < c; ++j) {
            float aj = fabsf(pexS[j]);
            rank += ((aj > ae) || (aj == ae && pidxS[j] < ne)) ? 1 : 0;
        }
        if (rank < S_) {
            cidx[(size_t)row * S_ + rank] = ne;
            cval[(size_t)row * S_ + rank] = pexS[e];
            yo[ne] = pexS[e];
        }
    }
}

// ---------------------------------------------------------------------------
// K3: sparse decoder + per-row squared-residual partial
// ---------------------------------------------------------------------------
__global__ __launch_bounds__(128) void decoder_kernel(const float* __restrict__ WdT,
                                                      const int* __restrict__ cidx,
                                                      const float* __restrict__ cval,
                                                      const float* __restrict__ kin,
                                                      float* __restrict__ khat,
                                                      float* __restrict__ partial) {
    int row = blockIdx.x;
    int l = row & (L_ - 1);
    int m = threadIdx.x;
    __shared__ int   sidx[S_];
    __shared__ float sval[S_];
    __shared__ float red[128];
    if (m < S_) { sidx[m] = cidx[(size_t)row * S_ + m]; sval[m] = cval[(size_t)row * S_ + m]; }
    __syncthreads();
    const float* wt = WdT + (size_t)l * N_ * M_;
    float acc = 0.0f;
    #pragma unroll
    for (int j = 0; j < S_; ++j)
        acc = fmaf(sval[j], wt[(size_t)sidx[j] * M_ + m], acc);
    khat[(size_t)row * M_ + m] = acc;
    float r = acc - kin[(size_t)row * M_ + m];
    red[m] = r * r;
    __syncthreads();
    for (int off = 64; off > 0; off >>= 1) {
        if (m < off) red[m] += red[m + off];
        __syncthreads();
    }
    if (m == 0) partial[row] = red[0];
}

// ---------------------------------------------------------------------------
// K4: deterministic reduction of 32768 partials -> loss
// ---------------------------------------------------------------------------
__global__ __launch_bounds__(256) void reduce_loss(const float* __restrict__ partial,
                                                   float* __restrict__ out_loss) {
    __shared__ float red[256];
    int tid = threadIdx.x;
    float s = 0.0f;
    for (int i = tid; i < ROWS; i += 256) s += partial[i];
    red[tid] = s;
    __syncthreads();
    for (int off = 128; off > 0; off >>= 1) {
        if (tid < off) red[tid] += red[tid + off];
        __syncthreads();
    }
    if (tid == 0) out_loss[0] = red[0] / (float)((size_t)B_ * L_ * M_);
}

// ---------------------------------------------------------------------------
extern "C" void kernel_launch(void* const* d_in, const int* in_sizes, int n_in,
                              void* d_out, int out_size, void* d_ws, size_t ws_size,
                              hipStream_t stream) {
    const float* kin = (const float*)d_in[0];   // [B][L][M]
    const float* We  = (const float*)d_in[1];   // [L][N][M]
    // d_in[2] = b_e (unused by reference encode())
    const float* Wd  = (const float*)d_in[3];   // [L][M][N]
    const float* bd  = (const float*)d_in[4];   // [L][M]
    // d_in[5] = s (==32, hardcoded)

    float* out   = (float*)d_out;
    float* loss  = out;                                   // [1]
    float* khat  = out + 1;                               // [B*L*M]
    float* y_out = out + 1 + (size_t)B_ * L_ * M_;        // [B*L*N]

    // workspace layout (region0 is shared: Wbf during encode, WdT after)
    char* ws = (char*)d_ws;
    unsigned short* Wbf = (unsigned short*)ws;                   // 64 MiB
    float*          WdT = (float*)ws;                            // 64 MiB (aliases Wbf)
    unsigned short* Abf = (unsigned short*)(ws + (64u << 20));   // 16 MiB
    float* cvec    = (float*)(ws + (80u << 20));                 // 512 KiB
    int*   cidx    = (int*)  (ws + (80u << 20) + (512u << 10));  // 4 MiB
    float* cval    = (float*)(ws + (84u << 20) + (512u << 10));  // 4 MiB
    float* partial = (float*)(ws + (88u << 20) + (512u << 10));  // 128 KiB

    bias_dot<<<dim3(N_ / 16, L_), 256, 0, stream>>>(We, bd, cvec);
    prep_a<<<(B_ * L_ * M_) / 256, 256, 0, stream>>>(kin, Abf);
    prep_w<<<(L_ * N_ * M_) / 256, 256, 0, stream>>>(We, Wbf);
    encoder_mfma<<<dim3(N_ / 128, B_ / 128, L_), 256, 0, stream>>>(
        Abf, Wbf, cvec, (unsigned short*)y_out);
    // Wbf dead now; transpose overwrites region0 with WdT
    transpose_wd<<<dim3(N_ / 32, M_ / 32, L_), 256, 0, stream>>>(Wd, WdT);
    topk_kernel<<<ROWS, 256, 0, stream>>>(y_out, We, kin, cvec, cidx, cval);
    decoder_kernel<<<ROWS, 128, 0, stream>>>(WdT, cidx, cval, kin, khat, partial);
    reduce_loss<<<1, 256, 0, stream>>>(partial, loss);
}

// Round 7
// 814.012 us; speedup vs baseline: 1.1098x; 1.1098x over previous
//
#include <hip/hip_runtime.h>
#include <hip/hip_bf16.h>

// Problem constants (fixed by the reference)
#define B_ 1024
#define L_ 32
#define M_ 128
#define N_ 4096
#define S_ 32
#define ROWS (B_ * L_)          // 32768 rows of length N_

typedef __attribute__((ext_vector_type(8))) short    short8_t;   // 8 bf16 (4 VGPR)
typedef __attribute__((ext_vector_type(8))) unsigned short ushort8_t;
typedef __attribute__((ext_vector_type(4))) float    f32x4;

__device__ __forceinline__ unsigned short f2bf(float x) {  // RNE bf16
    unsigned u = __float_as_uint(x);
    unsigned r = (u + 0x7FFFu + ((u >> 16) & 1u)) >> 16;
    return (unsigned short)r;
}
__device__ __forceinline__ float bf2f(unsigned short h) {
    return __uint_as_float((unsigned)h << 16);
}

// ---------------------------------------------------------------------------
// K0: transpose W_d [L][M][N] -> W_dT [L][N][M] (runs AFTER encoder; WdT
// aliases the Wbf region)
// ---------------------------------------------------------------------------
__global__ __launch_bounds__(256) void transpose_wd(const float* __restrict__ Wd,
                                                    float* __restrict__ WdT) {
    __shared__ float t[32][33];
    int l = blockIdx.z;
    int n0 = blockIdx.x * 32, m0 = blockIdx.y * 32;
    int tx = threadIdx.x & 31, ty = threadIdx.x >> 5;
    const float* src = Wd + (size_t)l * M_ * N_;
    for (int i = ty; i < 32; i += 8)
        t[i][tx] = src[(size_t)(m0 + i) * N_ + n0 + tx];
    __syncthreads();
    float* dst = WdT + (size_t)l * N_ * M_;
    for (int i = ty; i < 32; i += 8)
        dst[(size_t)(n0 + i) * M_ + m0 + tx] = t[tx][i];
}

// ---------------------------------------------------------------------------
// K0b: c[l][n] = dot(b_d[l], W_e[l][n])
// ---------------------------------------------------------------------------
__global__ __launch_bounds__(256) void bias_dot(const float* __restrict__ We,
                                                const float* __restrict__ bd,
                                                float* __restrict__ c) {
    int l = blockIdx.y;
    int tid = threadIdx.x;
    int nl = tid >> 4, l16 = tid & 15;
    int n = blockIdx.x * 16 + nl;
    const float* w = We + ((size_t)l * N_ + n) * M_ + l16 * 8;
    const float* b = bd + l * M_ + l16 * 8;
    float4 w0 = *(const float4*)(w), w1 = *(const float4*)(w + 4);
    float4 b0 = *(const float4*)(b), b1 = *(const float4*)(b + 4);
    float s = w0.x*b0.x + w0.y*b0.y + w0.z*b0.z + w0.w*b0.w
            + w1.x*b1.x + w1.y*b1.y + w1.z*b1.z + w1.w*b1.w;
    #pragma unroll
    for (int o = 8; o > 0; o >>= 1) s += __shfl_xor(s, o, 64);
    if (l16 == 0) c[(size_t)l * N_ + n] = s;
}

// ---------------------------------------------------------------------------
// P1: split kin -> Abf [l][b][256] bf16: seg0 = a1 = bf16(k), seg1 = a2 = bf16(k-a1)
// ---------------------------------------------------------------------------
__global__ __launch_bounds__(256) void prep_a(const float* __restrict__ kin,
                                              unsigned short* __restrict__ Abf) {
    int g = blockIdx.x * 256 + threadIdx.x;       // over B*L*M
    int b = g >> 12, l = (g >> 7) & 31, m = g & 127;
    float x = kin[g];
    unsigned short a1 = f2bf(x);
    unsigned short a2 = f2bf(x - bf2f(a1));
    size_t base = ((size_t)l * B_ + b) * 256;
    Abf[base + m]       = a1;
    Abf[base + 128 + m] = a2;
}

// P2: split We -> Wbf [l][n][256] bf16: seg0 = w1, seg1 = w2
__global__ __launch_bounds__(256) void prep_w(const float* __restrict__ We,
                                              unsigned short* __restrict__ Wbf) {
    int g = blockIdx.x * 256 + threadIdx.x;       // over L*N*M
    int l = g >> 19, n = (g >> 7) & 4095, m = g & 127;
    float x = We[g];
    unsigned short w1 = f2bf(x);
    unsigned short w2 = f2bf(x - bf2f(w1));
    size_t base = ((size_t)l * N_ + n) * 256;
    Wbf[base + m]       = w1;
    Wbf[base + 128 + m] = w2;
}

// ---------------------------------------------------------------------------
// K1: encoder approx GEMM via MFMA bf16, 3-term split (unchanged from round 4)
// ---------------------------------------------------------------------------
__device__ __forceinline__ int swz(int row) { return (row & 3) ^ ((row >> 2) & 3); }

__global__ __launch_bounds__(256) void encoder_mfma(const unsigned short* __restrict__ Abf,
                                                    const unsigned short* __restrict__ Wbf,
                                                    const float* __restrict__ cvec,
                                                    unsigned short* __restrict__ y16) {
    const int l   = blockIdx.z;
    const int bn0 = blockIdx.x * 128;
    const int bm0 = blockIdx.y * 128;
    __shared__ __align__(16) unsigned short As[128 * 32];
    __shared__ __align__(16) unsigned short Bs[128 * 32];
    const int tid  = threadIdx.x;
    const int lane = tid & 63, wave = tid >> 6;
    const int wr = wave >> 1, wc = wave & 1;

    const unsigned short* Ab = Abf + ((size_t)l * B_ + bm0) * 256;
    const unsigned short* Wb = Wbf + ((size_t)l * N_ + bn0) * 256;

    auto stage = [&](int kA0, int kW0) {
        #pragma unroll
        for (int i = 0; i < 2; ++i) {
            int p   = i * 256 + tid;
            int row = p >> 2;
            int lc  = (p & 3) ^ swz(row);
            const unsigned short* g = Ab + (size_t)row * 256 + kA0 + lc * 8;
            unsigned dst = (unsigned)((i * 256 + (tid & ~63)) * 16);
            __builtin_amdgcn_global_load_lds(
                (const __attribute__((address_space(1))) void*)g,
                (__attribute__((address_space(3))) void*)((char*)As + dst), 16, 0, 0);
        }
        #pragma unroll
        for (int i = 0; i < 2; ++i) {
            int p   = i * 256 + tid;
            int row = p >> 2;
            int lc  = (p & 3) ^ swz(row);
            const unsigned short* g = Wb + (size_t)row * 256 + kW0 + lc * 8;
            unsigned dst = (unsigned)((i * 256 + (tid & ~63)) * 16);
            __builtin_amdgcn_global_load_lds(
                (const __attribute__((address_space(1))) void*)g,
                (__attribute__((address_space(3))) void*)((char*)Bs + dst), 16, 0, 0);
        }
    };

    f32x4 acc[4][4];
    #pragma unroll
    for (int i = 0; i < 4; ++i)
        #pragma unroll
        for (int j = 0; j < 4; ++j) acc[i][j] = (f32x4){0.f, 0.f, 0.f, 0.f};

    stage(0, 0);
    __syncthreads();

    #pragma unroll
    for (int t = 0; t < 12; ++t) {
        short8_t aF[4], bF[4];
        const int kg = lane >> 4;
        #pragma unroll
        for (int mt = 0; mt < 4; ++mt) {
            int row = wr * 64 + mt * 16 + (lane & 15);
            int pc  = kg ^ swz(row);
            aF[mt] = *reinterpret_cast<const short8_t*>(As + row * 32 + pc * 8);
        }
        #pragma unroll
        for (int nt = 0; nt < 4; ++nt) {
            int row = wc * 64 + nt * 16 + (lane & 15);
            int pc  = kg ^ swz(row);
            bF[nt] = *reinterpret_cast<const short8_t*>(Bs + row * 32 + pc * 8);
        }
        #pragma unroll
        for (int mt = 0; mt < 4; ++mt)
            #pragma unroll
            for (int nt = 0; nt < 4; ++nt)
                acc[mt][nt] = __builtin_amdgcn_mfma_f32_16x16x32_bf16(
                    aF[mt], bF[nt], acc[mt][nt], 0, 0, 0);

        if (t < 11) {
            int tn  = t + 1;
            int seg = tn >> 2, r = (tn & 3) * 32;
            int ka  = (seg == 2) ? 128 + r : r;
            int kw  = (seg == 1) ? 128 + r : r;
            __syncthreads();
            stage(ka, kw);
            __syncthreads();
        }
    }

    #pragma unroll
    for (int nt = 0; nt < 4; ++nt) {
        int n = bn0 + wc * 64 + nt * 16 + (lane & 15);
        float cj = cvec[(size_t)l * N_ + n];
        #pragma unroll
        for (int mt = 0; mt < 4; ++mt) {
            #pragma unroll
            for (int j = 0; j < 4; ++j) {
                int b = bm0 + wr * 64 + mt * 16 + (lane >> 4) * 4 + j;
                y16[((size_t)(b * L_ + l)) * 8192 + n] = f2bf(acc[mt][nt][j] - cj);
            }
        }
    }
}

// ---------------------------------------------------------------------------
// K2: SELECTOR ONLY (no y writes). Bisect on bf16 approx, pool >= lo-MARGIN,
// exact recompute = round-4's verbatim thread-per-candidate ascending-m global
// chain (bit-identical to the r1-r4/r6 passing order), exact all-pairs rank.
// Emits cidx/cval only. Tiny LDS -> high occupancy.
// ---------------------------------------------------------------------------
#define POOL 64
#define MARGIN 8e-4f

__global__ __launch_bounds__(256) void topk_sel(const float* __restrict__ y,
                                                const float* __restrict__ We,
                                                const float* __restrict__ kin,
                                                const float* __restrict__ cvec,
                                                int* __restrict__ cidx,
                                                float* __restrict__ cval) {
    const int row = blockIdx.x;                 // row = b*L + l
    const int b = row >> 5, l = row & 31;
    const unsigned short* ya = (const unsigned short*)y + (size_t)row * 8192;
    const int tid  = threadIdx.x;
    const int wave = tid >> 6, lane = tid & 63;

    __shared__ float kinL[M_];
    __shared__ float red_f[4];
    __shared__ int   red_i[2][4];
    __shared__ int   pidxS[POOL];
    __shared__ float pexS[POOL];
    __shared__ int   pcnt;

    if (tid < M_) kinL[tid] = kin[((size_t)b * L_ + l) * M_ + tid];
    if (tid == 0) pcnt = 0;

    // load 16 approx values (two 16B loads), thread-local slots
    ushort8_t u0 = *reinterpret_cast<const ushort8_t*>(ya + tid * 8);
    ushort8_t u1 = *reinterpret_cast<const ushort8_t*>(ya + 2048 + tid * 8);
    float a[16];
    #pragma unroll
    for (int i = 0; i < 8; ++i) {
        a[i]     = fabsf(bf2f(u0[i]));
        a[8 + i] = fabsf(bf2f(u1[i]));
    }

    // block max (one barrier)
    float mx = 0.0f;
    #pragma unroll
    for (int i = 0; i < 16; ++i) mx = fmaxf(mx, a[i]);
    #pragma unroll
    for (int o = 32; o > 0; o >>= 1) mx = fmaxf(mx, __shfl_xor(mx, o, 64));
    if (lane == 0) red_f[wave] = mx;
    __syncthreads();
    mx = fmaxf(fmaxf(red_f[0], red_f[1]), fmaxf(red_f[2], red_f[3]));

    // bisect: invariant count(a >= lo) >= 32; tighten until count <= 40.
    // ONE barrier per iteration (alternating slots).
    float lo = 0.0f, hi = mx;
    int cl = N_;
    for (int it = 0; it < 30 && cl > 40; ++it) {
        float t = 0.5f * (lo + hi);
        int c = 0;
        #pragma unroll
        for (int i = 0; i < 16; ++i) c += (a[i] >= t) ? 1 : 0;
        #pragma unroll
        for (int o = 32; o > 0; o >>= 1) c += __shfl_xor(c, o, 64);
        if (lane == 0) red_i[it & 1][wave] = c;
        __syncthreads();
        c = red_i[it & 1][0] + red_i[it & 1][1] + red_i[it & 1][2] + red_i[it & 1][3];
        if (c >= S_) { lo = t; cl = c; } else { hi = t; }
    }

    // pool: everything with approx >= lo - MARGIN (provably covers exact top-32)
    const float th = lo - MARGIN;
    #pragma unroll
    for (int i = 0; i < 16; ++i) {
        if (a[i] >= th) {
            int p = atomicAdd(&pcnt, 1);
            if (p < POOL) pidxS[p] = (i < 8) ? (tid * 8 + i) : (2048 + tid * 8 + i - 8);
        }
    }
    __syncthreads();
    int c = pcnt < POOL ? pcnt : POOL;

    // exact recompute: ascending-m scalar fmaf chain from GLOBAL (We rows are
    // L3-resident; contiguous 512B per thread). Verbatim round-4 passing code.
    for (int e = tid; e < c; e += 256) {
        int n = pidxS[e];
        const float* w = We + ((size_t)l * N_ + n) * M_;
        float acc = -cvec[(size_t)l * N_ + n];
        #pragma unroll 8
        for (int m = 0; m < M_; ++m) acc = fmaf(w[m], kinL[m], acc);
        pexS[e] = acc;
    }
    __syncthreads();

    // exact rank (lowest-index tie-break), emit winners (compact lists only)
    for (int e = tid; e < c; e += 256) {
        float ae = fabsf(pexS[e]);
        int   ne = pidxS[e];
        int rank = 0;
        for (int j = 0; j < c; ++j) {
            float aj = fabsf(pexS[j]);
            rank += ((aj > ae) || (aj == ae && pidxS[j] < ne)) ? 1 : 0;
        }
        if (rank < S_) {
            cidx[(size_t)row * S_ + rank] = ne;
            cval[(size_t)row * S_ + rank] = pexS[e];
        }
    }
}

// ---------------------------------------------------------------------------
// K3: STREAMING: zero y row + scatter winners + sparse decode + residual.
// One block per row; write-bound, tiny LDS, max occupancy.
// ---------------------------------------------------------------------------
__global__ __launch_bounds__(256) void decode_scatter(const float* __restrict__ WdT,
                                                      const int* __restrict__ cidx,
                                                      const float* __restrict__ cval,
                                                      const float* __restrict__ kin,
                                                      float* __restrict__ y,
                                                      float* __restrict__ khat,
                                                      float* __restrict__ partial) {
    const int row = blockIdx.x;
    const int l = row & (L_ - 1);
    const int tid = threadIdx.x;
    __shared__ int   sidx[S_];
    __shared__ float sval[S_];
    __shared__ float red[128];

    if (tid < S_) { sidx[tid] = cidx[(size_t)row * S_ + tid]; sval[tid] = cval[(size_t)row * S_ + tid]; }

    // zero the full 16KB y row (coalesced float4)
    float* yo = y + (size_t)row * N_;
    float4 z = {0.f, 0.f, 0.f, 0.f};
    #pragma unroll
    for (int i = 0; i < 4; ++i)
        *reinterpret_cast<float4*>(yo + 4 * (tid + i * 256)) = z;
    __syncthreads();   // drains zero-stores; sidx/sval visible

    // scatter the 32 winners
    if (tid < S_) yo[sidx[tid]] = sval[tid];

    // sparse decode: thread m in [0,128)
    if (tid < M_) {
        const float* wt = WdT + (size_t)l * N_ * M_;
        float acc = 0.0f;
        #pragma unroll
        for (int j = 0; j < S_; ++j)
            acc = fmaf(sval[j], wt[(size_t)sidx[j] * M_ + tid], acc);
        khat[(size_t)row * M_ + tid] = acc;
        float r = acc - kin[(size_t)row * M_ + tid];
        red[tid] = r * r;
    }
    __syncthreads();
    for (int off = 64; off > 0; off >>= 1) {
        if (tid < off) red[tid] += red[tid + off];
        __syncthreads();
    }
    if (tid == 0) partial[row] = red[0];
}

// ---------------------------------------------------------------------------
// K4: deterministic reduction of 32768 partials -> loss
// ---------------------------------------------------------------------------
__global__ __launch_bounds__(256) void reduce_loss(const float* __restrict__ partial,
                                                   float* __restrict__ out_loss) {
    __shared__ float red[256];
    int tid = threadIdx.x;
    float s = 0.0f;
    for (int i = tid; i < ROWS; i += 256) s += partial[i];
    red[tid] = s;
    __syncthreads();
    for (int off = 128; off > 0; off >>= 1) {
        if (tid < off) red[tid] += red[tid + off];
        __syncthreads();
    }
    if (tid == 0) out_loss[0] = red[0] / (float)((size_t)B_ * L_ * M_);
}

// ---------------------------------------------------------------------------
extern "C" void kernel_launch(void* const* d_in, const int* in_sizes, int n_in,
                              void* d_out, int out_size, void* d_ws, size_t ws_size,
                              hipStream_t stream) {
    const float* kin = (const float*)d_in[0];   // [B][L][M]
    const float* We  = (const float*)d_in[1];   // [L][N][M]
    // d_in[2] = b_e (unused by reference encode())
    const float* Wd  = (const float*)d_in[3];   // [L][M][N]
    const float* bd  = (const float*)d_in[4];   // [L][M]
    // d_in[5] = s (==32, hardcoded)

    float* out   = (float*)d_out;
    float* loss  = out;                                   // [1]
    float* khat  = out + 1;                               // [B*L*M]
    float* y_out = out + 1 + (size_t)B_ * L_ * M_;        // [B*L*N]

    // workspace layout (region0 is shared: Wbf during encode, WdT after)
    char* ws = (char*)d_ws;
    unsigned short* Wbf = (unsigned short*)ws;                   // 64 MiB
    float*          WdT = (float*)ws;                            // 64 MiB (aliases Wbf)
    unsigned short* Abf = (unsigned short*)(ws + (64u << 20));   // 16 MiB
    float* cvec    = (float*)(ws + (80u << 20));                 // 512 KiB
    int*   cidx    = (int*)  (ws + (80u << 20) + (512u << 10));  // 4 MiB
    float* cval    = (float*)(ws + (84u << 20) + (512u << 10));  // 4 MiB
    float* partial = (float*)(ws + (88u << 20) + (512u << 10));  // 128 KiB

    bias_dot<<<dim3(N_ / 16, L_), 256, 0, stream>>>(We, bd, cvec);
    prep_a<<<(B_ * L_ * M_) / 256, 256, 0, stream>>>(kin, Abf);
    prep_w<<<(L_ * N_ * M_) / 256, 256, 0, stream>>>(We, Wbf);
    encoder_mfma<<<dim3(N_ / 128, B_ / 128, L_), 256, 0, stream>>>(
        Abf, Wbf, cvec, (unsigned short*)y_out);
    // Wbf dead now; transpose overwrites region0 with WdT
    transpose_wd<<<dim3(N_ / 32, M_ / 32, L_), 256, 0, stream>>>(Wd, WdT);
    // selection (reads approx from y region low-halves; writes cidx/cval only)
    topk_sel<<<ROWS, 256, 0, stream>>>(y_out, We, kin, cvec, cidx, cval);
    // streaming: zero+scatter y, decode khat, residual partials
    decode_scatter<<<ROWS, 256, 0, stream>>>(WdT, cidx, cval, kin, y_out, khat, partial);
    reduce_loss<<<1, 256, 0, stream>>>(partial, loss);
}